// Round 7
// baseline (411.333 us; speedup 1.0000x reference)
//
#include <hip/hip_runtime.h>
#include <math.h>

#define DIM 32
#define NK  16
#define LOG2E 1.4426950408889634f

typedef __attribute__((ext_vector_type(8))) short bf16x8;
typedef __attribute__((ext_vector_type(4))) float f32x4;

#define MFMA16 __builtin_amdgcn_mfma_f32_16x16x32_bf16

// ws layout (precomputed every launch). W frags LANE-LINEAR: f=[k][o16][lane]
#define WHIF_OFF 0       // [16][2][64] 16B hi frags = 32768 B (staged to LDS)
#define WLOF_OFF 32768   // [16][2][64] 16B lo frags = 32768 B (global/L1)
#define HH_OFF  65536
#define HL_OFF  66560
#define GH_OFF  67584
#define GL_OFF  68608
#define CG_OFF  69632    // [NK] f32 gate constant

typedef __attribute__((address_space(1))) const unsigned int gu32;
typedef __attribute__((address_space(3))) unsigned int lu32;

// LDS: whi 32KB | per-wave lds_p (144B stride, conflict-free) | per-wave bias
#define LDSP_BASE 32768
#define LDSP_WAVE 2304
#define LDSB_BASE (32768 + 4 * 2304)    // 41984
#define LDSB_WAVE 2048
#define LDS_TOTAL (41984 + 4 * 2048)    // 50176 -> 3 blocks/CU

__device__ __forceinline__ void split2(float x, short* hi, short* lo) {
  unsigned u = __float_as_uint(x);
  *hi = (short)(u >> 16);
  float hf = __uint_as_float(u & 0xFFFF0000u);
  float l = x - hf;
  *lo = (short)(__float_as_uint(l) >> 16);
}

__global__ __launch_bounds__(256) void gmm_setup_kernel(
    const float* __restrict__ mu, const float* __restrict__ logsigma,
    const float* __restrict__ W, char* __restrict__ ws)
{
  int i = blockIdx.x * 256 + threadIdx.x;
  if (i < NK * 2 * 64) {
    const int k = i >> 7, o16 = (i >> 6) & 1, lane = i & 63;
    const int c = lane & 15, g = lane >> 4;
    const int o = o16 * 16 + c;
    bf16x8 hi, lo;
    #pragma unroll
    for (int j = 0; j < 8; ++j) {
      short h_, l_;
      split2(W[(k * DIM + o) * DIM + g * 8 + j], &h_, &l_);
      hi[j] = h_; lo[j] = l_;
    }
    ((bf16x8*)(ws + WHIF_OFF))[i] = hi;
    ((bf16x8*)(ws + WLOF_OFF))[i] = lo;
  }
  if (i < NK * DIM) {
    float s2 = __expf(2.0f * logsigma[i]);
    float h = (-0.5f / s2) * LOG2E;
    float g = (mu[i] / s2) * LOG2E;
    short a, b;
    split2(h, &a, &b);
    ((short*)(ws + HH_OFF))[i] = a; ((short*)(ws + HL_OFF))[i] = b;
    split2(g, &a, &b);
    ((short*)(ws + GH_OFF))[i] = a; ((short*)(ws + GL_OFF))[i] = b;
  }
  if (i < NK) {
    float acc = 0.0f;
    for (int d = 0; d < DIM; ++d) {
      float s2 = __expf(2.0f * logsigma[i * DIM + d]);
      float m  = mu[i * DIM + d];
      acc += m * m * (-0.5f / s2) * LOG2E - 0.5f * log2f(6.283185307179586f * s2);
    }
    ((float*)(ws + CG_OFF))[i] = acc;
  }
}

// ABLATION PROBE. MODE: 0=full(real output) 1=noGate 2=noWmem(+noBarrier)
// 3=noEpilogue 4=noWmem+noEpilogue (MFMA floor + gate).
// All modes: 256 thr = 4 waves x M=32 (2 tiles of 16); grid runs batch 3x
// (blockIdx & 2047) purely so each dispatch is individually visible in the
// rocprof top-5 next to ~43us poison fills. Divide dur_us by 3.
template <int MODE>
__global__ __launch_bounds__(256, 3) void gmm_probe(
    const float* __restrict__ x,
    const float* __restrict__ bias,
    const char* __restrict__ ws,
    float* __restrict__ outp)
{
  constexpr bool WMEM = (MODE != 2 && MODE != 4);   // W/bias memory + barrier
  constexpr bool GATE = (MODE != 1);                // gate MFMA+exp2+shfl
  constexpr bool EPI  = (MODE != 3 && MODE != 4);   // lds_p read + max/fma

  __shared__ char lds[LDS_TOTAL];
  const int tid  = threadIdx.x;
  const int wid  = tid >> 6;
  const int lane = tid & 63;
  const int g = lane >> 4;
  const int c = lane & 15;
  const int bid = (int)blockIdx.x & 2047;
  const int sbase = (bid * 4 + wid) * 32;

  if constexpr (WMEM) {
    // stage whi frags (32KB) to LDS
    #pragma unroll
    for (int r = 0; r < 8; ++r) {
      const int off = r * 4096 + wid * 1024;
      __builtin_amdgcn_global_load_lds(
          (gu32*)(ws + WHIF_OFF + off + lane * 16), (lu32*)(lds + off), 16, 0, 0);
    }
    // stage bias wave-locally (2KB/wave; read later by same wave, no barrier dep)
    const float4* bsrc = (const float4*)bias;
    *(float4*)(lds + LDSB_BASE + wid * LDSB_WAVE + lane * 32)      = bsrc[lane * 2];
    *(float4*)(lds + LDSB_BASE + wid * LDSB_WAVE + lane * 32 + 16) = bsrc[lane * 2 + 1];
  }

  // x loads (2 tiles x 32B/lane)
  float4 xa[2][2];
  #pragma unroll
  for (int t = 0; t < 2; ++t) {
    const float4* xp =
        (const float4*)(x + (size_t)(sbase + t * 16 + c) * DIM + g * 8);
    xa[t][0] = xp[0];
    xa[t][1] = xp[1];
  }

  bf16x8 xh[2], xl[2];
  f32x4 wv[2];
  #pragma unroll
  for (int t = 0; t < 2; ++t) {
    float xv[8] = {xa[t][0].x, xa[t][0].y, xa[t][0].z, xa[t][0].w,
                   xa[t][1].x, xa[t][1].y, xa[t][1].z, xa[t][1].w};
    bf16x8 x2h, x2l;
    #pragma unroll
    for (int j = 0; j < 8; ++j) {
      short h_, l_;
      split2(xv[j], &h_, &l_);
      xh[t][j] = h_; xl[t][j] = l_;
      if constexpr (GATE) {
        float q = xv[j] * xv[j];
        split2(q, &h_, &l_);
        x2h[j] = h_; x2l[j] = l_;
      }
    }
    if constexpr (GATE) {
      const bf16x8 fhh = ((const bf16x8*)(ws + HH_OFF))[c * 4 + g];
      const bf16x8 fhl = ((const bf16x8*)(ws + HL_OFF))[c * 4 + g];
      const bf16x8 fgh = ((const bf16x8*)(ws + GH_OFF))[c * 4 + g];
      const bf16x8 fgl = ((const bf16x8*)(ws + GL_OFF))[c * 4 + g];
      const float  cgv = ((const float*)(ws + CG_OFF))[c];
      f32x4 e = {cgv, cgv, cgv, cgv};
      e = MFMA16(x2h,   fhh, e, 0, 0, 0);
      e = MFMA16(x2l,   fhh, e, 0, 0, 0);
      e = MFMA16(x2h,   fhl, e, 0, 0, 0);
      e = MFMA16(xh[t], fgh, e, 0, 0, 0);
      e = MFMA16(xl[t], fgh, e, 0, 0, 0);
      e = MFMA16(xh[t], fgl, e, 0, 0, 0);
      #pragma unroll
      for (int r = 0; r < 4; ++r) {
        float p = __builtin_amdgcn_exp2f(e[r]);
        float s = p;
        s += __shfl_xor(s, 1, 64);
        s += __shfl_xor(s, 2, 64);
        s += __shfl_xor(s, 4, 64);
        s += __shfl_xor(s, 8, 64);
        wv[t][r] = p * __builtin_amdgcn_rcpf(s);
      }
    } else {
      wv[t] = (f32x4){1.0f, 1.0f, 1.0f, 1.0f};
    }
  }

  if constexpr (EPI) {
    // transpose gate weights through conflict-free padded lds_p (wave-local)
    char* pw = lds + LDSP_BASE + wid * LDSP_WAVE + c * 144 + g * 16;
    *(f32x4*)(pw)      = wv[0];
    *(f32x4*)(pw + 64) = wv[1];
  }

  if constexpr (WMEM) __syncthreads();   // drains vmcnt(0): staging complete

  const bf16x8* wlof = (const bf16x8*)(ws + WLOF_OFF);
  const char*   ldsp = lds + LDSP_BASE + wid * LDSP_WAVE + g * 16;
  f32x4 o0[2], o1[2];
  #pragma unroll
  for (int t = 0; t < 2; ++t) { o0[t] = (f32x4){0,0,0,0}; o1[t] = (f32x4){0,0,0,0}; }

  #pragma unroll
  for (int k = 0; k < NK; ++k) {
    bf16x8 w0h, w1h, w0l, w1l;
    float b0, b1;
    if constexpr (WMEM) {
      w0h = *(const bf16x8*)(lds + (k * 2 + 0) * 1024 + lane * 16);
      w1h = *(const bf16x8*)(lds + (k * 2 + 1) * 1024 + lane * 16);
      w0l = wlof[(k * 2 + 0) * 64 + lane];
      w1l = wlof[(k * 2 + 1) * 64 + lane];
      b0 = *(const float*)(lds + LDSB_BASE + wid * LDSB_WAVE + k * 128 + c * 4);
      b1 = *(const float*)(lds + LDSB_BASE + wid * LDSB_WAVE + k * 128 + 64 + c * 4);
    } else {
      w0h = xh[0]; w1h = xl[0]; w0l = xh[1]; w1l = xl[1];
      b0 = 0.5f; b1 = 0.25f;
    }
    #pragma unroll
    for (int t = 0; t < 2; ++t) {
      if constexpr (EPI) {
        f32x4 s0 = {b0, b0, b0, b0}, s1 = {b1, b1, b1, b1};
        s0 = MFMA16(xh[t], w0h, s0, 0, 0, 0);
        s0 = MFMA16(xl[t], w0h, s0, 0, 0, 0);
        s0 = MFMA16(xh[t], w0l, s0, 0, 0, 0);
        s1 = MFMA16(xh[t], w1h, s1, 0, 0, 0);
        s1 = MFMA16(xl[t], w1h, s1, 0, 0, 0);
        s1 = MFMA16(xh[t], w1l, s1, 0, 0, 0);
        const f32x4 wb = *(const f32x4*)(ldsp + k * 144 + t * 64);
        const f32x4 z = {0.0f, 0.0f, 0.0f, 0.0f};
        o0[t] = __builtin_elementwise_fma(wb, __builtin_elementwise_max(s0, z), o0[t]);
        o1[t] = __builtin_elementwise_fma(wb, __builtin_elementwise_max(s1, z), o1[t]);
      } else {
        // MFMA-direct accumulate: no lds_p read, no max/fma epilogue
        o0[t] = MFMA16(xh[t], w0h, o0[t], 0, 0, 0);
        o0[t] = MFMA16(xl[t], w0h, o0[t], 0, 0, 0);
        o0[t] = MFMA16(xh[t], w0l, o0[t], 0, 0, 0);
        o1[t] = MFMA16(xh[t], w1h, o1[t], 0, 0, 0);
        o1[t] = MFMA16(xl[t], w1h, o1[t], 0, 0, 0);
        o1[t] = MFMA16(xh[t], w1l, o1[t], 0, 0, 0);
      }
    }
  }

  if constexpr (!EPI) {
    // keep the gate live (rule #17): fold wv into the stored result
    #pragma unroll
    for (int t = 0; t < 2; ++t) { o0[t] = o0[t] + wv[t]; o1[t] = o1[t] + wv[t]; }
  }

  #pragma unroll
  for (int t = 0; t < 2; ++t) {
    #pragma unroll
    for (int r = 0; r < 4; ++r) {
      size_t row = (size_t)(sbase + t * 16 + g * 4 + r);
      outp[row * DIM + c]      = o0[t][r];
      outp[row * DIM + 16 + c] = o1[t][r];
    }
  }
}

extern "C" void kernel_launch(void* const* d_in, const int* in_sizes, int n_in,
                              void* d_out, int out_size, void* d_ws, size_t ws_size,
                              hipStream_t stream) {
  const float* x  = (const float*)d_in[0];
  const float* mu = (const float*)d_in[1];
  const float* ls = (const float*)d_in[2];
  const float* W  = (const float*)d_in[3];
  const float* bv = (const float*)d_in[4];
  float* out = (float*)d_out;
  const int B = in_sizes[0] / DIM;

  gmm_setup_kernel<<<8, 256, 0, stream>>>(mu, ls, W, (char*)d_ws);

  // 3x grid on every probe so each dispatch clears the ~43us poison fills
  // and is individually visible in rocprof; batch index = blockIdx & 2047.
  const int GRID = (B / 128) * 3;

  // scratch output regions for ablation variants (junk values, DCE anchors)
  auto vout = [&](int m) -> float* {
    size_t off = (size_t)(1u << 20) + (size_t)(m - 1) * (33u << 20);
    if (off + (32u << 20) > ws_size) off = (size_t)(1u << 20);
    return (float*)((char*)d_ws + off);
  };

  gmm_probe<0><<<GRID, 256, 0, stream>>>(x, bv, (const char*)d_ws, out);
  gmm_probe<1><<<GRID, 256, 0, stream>>>(x, bv, (const char*)d_ws, vout(1));
  gmm_probe<2><<<GRID, 256, 0, stream>>>(x, bv, (const char*)d_ws, vout(2));
  gmm_probe<3><<<GRID, 256, 0, stream>>>(x, bv, (const char*)d_ws, vout(3));
  gmm_probe<4><<<GRID, 256, 0, stream>>>(x, bv, (const char*)d_ws, vout(4));
}